// Round 2
// baseline (180.345 us; speedup 1.0000x reference)
//
#include <hip/hip_runtime.h>
#include <math.h>

// EUNN layer, H=1024: 16 steps of (even + odd) pairwise complex rotations + final phase.
// v6 = v4 (R=2, best measured config) + NON-TEMPORAL x loads / out stores.
// Post-mortem of v5 (R=1, 2x waves): occupancy 15->29%, VALUBusy 42->51%, but dur
// 52.6->62.4 us -- more TLP did NOT fill the stalls => shared-resource stall, not
// per-wave latency. Theory: the 64 MB x/out stream flows through each XCD L2 and
// evicts the 256 KB coeff table, so per-step coeff loads miss to L3/HBM (~400-900
// cyc) instead of hitting L2 (~200 cyc); compute cover (~190 cyc) can't hide that.
// nt load/store keeps the stream from polluting L2 -> coeff loads stay L2-resident.
//
// ws layout (f4 units): coeff_t[s][phase][512], slot k = (j&7)*64 + (j>>3) for pair j
//   (phase 0 = even pairs 0..511; phase 1 = odd pairs 0..510 + identity pad 511)
// omega (f4 = 2 elements (c,s,c,s)) transposed the same way at float offset 65536.

typedef float f4 __attribute__((ext_vector_type(4)));

#define OMCS_OFF 65536

__global__ __launch_bounds__(256) void eunn_precompute(
    const float* __restrict__ omega, const float* __restrict__ et,
    const float* __restrict__ ot, const float* __restrict__ ep,
    const float* __restrict__ op, float* __restrict__ ws) {
  int tid = blockIdx.x * 256 + threadIdx.x;
  if (tid < 16384) {
    int s = tid >> 10, k = tid & 1023;
    int phase = k >> 9, j = k & 511;
    float ct, st, cp, sp;
    if (phase == 0) {
      sincosf(et[s * 512 + j], &st, &ct);
      sincosf(ep[s * 512 + j], &sp, &cp);
    } else if (j < 511) {
      sincosf(ot[s * 511 + j], &st, &ct);
      sincosf(op[s * 511 + j], &sp, &cp);
    } else {  // identity pad pair (elements 1023/1024)
      ct = 1.f; st = 0.f; cp = 0.f; sp = 1.f;
    }
    // transposed slot: lane = j>>3 owns pair j as its (j&7)-th register
    ((f4*)ws)[s * 1024 + phase * 512 + (j & 7) * 64 + (j >> 3)] =
        (f4){ct, st, cp, sp};
  } else if (tid < 16896) {
    int m = tid - 16384;  // f4 index covering elements 2m, 2m+1
    float s0, c0, s1, c1;
    sincosf(omega[2 * m], &s0, &c0);
    sincosf(omega[2 * m + 1], &s1, &c1);
    ((f4*)(ws + OMCS_OFF))[(m & 7) * 64 + (m >> 3)] = (f4){c0, s0, c1, s1};
  }
}

// One wave owns R rows; lane l owns elements 16l..16l+15 (8 even pairs).
// Even rotations register-local; odd rotations register-local except one
// boundary pair per lane (intra-wave shfl). Pipeline: O loads issue before
// even compute; next step's E loads issue after even compute.
template <int R>
__global__ __launch_bounds__(256, 2) void eunn_main(
    const float* __restrict__ x, float* __restrict__ out,
    const float* __restrict__ ws) {
  const int lane = threadIdx.x & 63;
  const int wid = blockIdx.x * (blockDim.x >> 6) + (threadIdx.x >> 6);
  const f4* cf = (const f4*)ws + lane;  // + p*64 + s*1024 (+512 for odd)

  // e[r][p] = (re[16l+2p], im[16l+2p], re[16l+2p+1], im[16l+2p+1])
  f4 e[R][8];
#pragma unroll
  for (int r = 0; r < R; ++r) {
    const f4* xr = (const f4*)(x + (size_t)(wid * R + r) * 2048) + lane * 8;
#pragma unroll
    for (int p = 0; p < 8; ++p) e[r][p] = __builtin_nontemporal_load(&xr[p]);
  }

  f4 E[8];  // current step's even coeffs (ct,st,cp,sp per pair)
#pragma unroll
  for (int p = 0; p < 8; ++p) E[p] = cf[p * 64];

#pragma unroll 1
  for (int s = 0; s < 16; ++s) {
    // ---- issue odd coeff loads (completion covered by even compute) ----
    f4 O[8];
    {
      const f4* ob = cf + s * 1024 + 512;
#pragma unroll
      for (int p = 0; p < 8; ++p) O[p] = ob[p * 64];
    }
    // ---- even rotation: pair j=8l+p couples (e.x,e.y) and (e.z,e.w) ----
#pragma unroll
    for (int r = 0; r < R; ++r) {
#pragma unroll
      for (int p = 0; p < 8; ++p) {
        f4 c = E[p];
        f4 v = e[r][p];
        float t0 = c.x * v.x - c.y * v.z;
        float t1 = c.x * v.y - c.y * v.w;
        e[r][p] = (f4){c.w * t0 - c.z * t1, c.z * t0 + c.w * t1,
                       c.y * v.x + c.x * v.z, c.y * v.y + c.x * v.w};
      }
    }
    // ---- load next step's even coeffs into E (covered by odd compute) ----
    {
      const f4* nb = cf + ((s + 1) & 15) * 1024;
#pragma unroll
      for (int p = 0; p < 8; ++p) E[p] = nb[p * 64];
    }
    // ---- odd rotation: pair j couples elements 2j+1, 2j+2 ----
    {
      // neighbor pair (8l-1)'s (ct,st) from lane l-1; identity at lane 0
      float ctm = __shfl_up(O[7].x, 1, 64);
      float stm = __shfl_up(O[7].y, 1, 64);
      if (lane == 0) { ctm = 1.f; stm = 0.f; }
#pragma unroll
      for (int r = 0; r < R; ++r) {
        float upx = __shfl_down(e[r][0].x, 1, 64);  // elem 16l+16 (pre)
        float upy = __shfl_down(e[r][0].y, 1, 64);
        float dnz = __shfl_up(e[r][7].z, 1, 64);    // elem 16l-1 (pre)
        float dnw = __shfl_up(e[r][7].w, 1, 64);
        // element 16l = second half of pair 8l-1
        float nx = stm * dnz + ctm * e[r][0].x;
        float ny = stm * dnw + ctm * e[r][0].y;
        e[r][0].x = nx;
        e[r][0].y = ny;
        // interior odd pairs j=8l+p, p=0..6
#pragma unroll
        for (int p = 0; p < 7; ++p) {
          f4 c = O[p];
          float e0r = e[r][p].z, e0i = e[r][p].w;
          float e1r = e[r][p + 1].x, e1i = e[r][p + 1].y;
          float t0 = c.x * e0r - c.y * e1r;
          float t1 = c.x * e0i - c.y * e1i;
          e[r][p].z = c.w * t0 - c.z * t1;
          e[r][p].w = c.z * t0 + c.w * t1;
          e[r][p + 1].x = c.y * e0r + c.x * e1r;
          e[r][p + 1].y = c.y * e0i + c.x * e1i;
        }
        // boundary pair j=8l+7 (second element lives in lane l+1; lane 63 = identity)
        {
          f4 c = O[7];
          float e0r = e[r][7].z, e0i = e[r][7].w;
          float t0 = c.x * e0r - c.y * upx;
          float t1 = c.x * e0i - c.y * upy;
          e[r][7].z = c.w * t0 - c.z * t1;
          e[r][7].w = c.z * t0 + c.w * t1;
        }
      }
    }
  }

  // ---- final diagonal phase + store ----
  const f4* om4 = (const f4*)(ws + OMCS_OFF) + lane;  // (c,s,c,s), + p*64
#pragma unroll
  for (int r = 0; r < R; ++r) {
    f4* outr = (f4*)(out + (size_t)(wid * R + r) * 2048) + lane * 8;
#pragma unroll
    for (int p = 0; p < 8; ++p) {
      f4 v = e[r][p];
      f4 w = om4[p * 64];
      f4 res = (f4){v.x * w.x - v.y * w.y, v.x * w.y + v.y * w.x,
                    v.z * w.z - v.w * w.w, v.z * w.w + v.w * w.z};
      __builtin_nontemporal_store(res, &outr[p]);
    }
  }
}

extern "C" void kernel_launch(void* const* d_in, const int* in_sizes, int n_in,
                              void* d_out, int out_size, void* d_ws, size_t ws_size,
                              hipStream_t stream) {
  const float* x     = (const float*)d_in[0];  // (4096,1024,2)
  const float* omega = (const float*)d_in[1];  // (1024,)
  const float* et    = (const float*)d_in[2];  // (16,512)
  const float* ot    = (const float*)d_in[3];  // (16,511)
  const float* ep    = (const float*)d_in[4];  // (16,512)
  const float* op    = (const float*)d_in[5];  // (16,511)
  float* out = (float*)d_out;
  float* ws  = (float*)d_ws;

  // 16896 jobs: 16x1024 coeff quads + 512 omega f4 entries
  eunn_precompute<<<dim3(66), dim3(256), 0, stream>>>(omega, et, ot, ep, op, ws);

  // R=2 rows/wave: 2048 waves, 4 waves/block -> 512 blocks
  eunn_main<2><<<dim3(512), dim3(256), 0, stream>>>(x, out, ws);
}

// Round 3
// 129.990 us; speedup vs baseline: 1.3874x; 1.3874x over previous
//
#include <hip/hip_runtime.h>
#include <math.h>

// EUNN layer, H=1024: 16 steps of (even + odd) pairwise complex rotations + final phase.
// v7 = v4 (best measured, 52.6us) + LDS coeff staging (block-shared, double-buffered).
// Post-mortems: v5 (2x TLP) raised VALUBusy only 42->51% and REGRESSED -> stalls are
// correlated on a shared resource. v6 (NT stores) exploded WRITE_SIZE 40->102MB
// (partial-line 16B stores no longer merged in L2) -> reverted. FETCH_SIZE 18MB < x's
// 32MB proves coeffs were already cache-hits; the bottleneck is L2 *bandwidth/queueing*:
// every wave re-reads the full 256KB coeff table (512MB total L2 reads, all waves
// hitting the same hot 16KB step-block concurrently). v7 shares one copy per block:
// 4 waves x 16KB/step staged into LDS double-buffer (32KB), one-step prefetch
// (issue global loads at step top, ds_write + barrier at step end) -> L2 coeff
// traffic /4, coeff reads become conflict-free ds_read_b128 off the L2 critical path.
//
// ws layout (f4 units): coeff_t[s][phase][512], slot k = (j&7)*64 + (j>>3) for pair j
//   (phase 0 = even pairs 0..511; phase 1 = odd pairs 0..510 + identity pad 511)
// omega (f4 = 2 elements (c,s,c,s)) transposed the same way at float offset 65536.

typedef float f4 __attribute__((ext_vector_type(4)));

#define OMCS_OFF 65536

__global__ __launch_bounds__(256) void eunn_precompute(
    const float* __restrict__ omega, const float* __restrict__ et,
    const float* __restrict__ ot, const float* __restrict__ ep,
    const float* __restrict__ op, float* __restrict__ ws) {
  int tid = blockIdx.x * 256 + threadIdx.x;
  if (tid < 16384) {
    int s = tid >> 10, k = tid & 1023;
    int phase = k >> 9, j = k & 511;
    float ct, st, cp, sp;
    if (phase == 0) {
      sincosf(et[s * 512 + j], &st, &ct);
      sincosf(ep[s * 512 + j], &sp, &cp);
    } else if (j < 511) {
      sincosf(ot[s * 511 + j], &st, &ct);
      sincosf(op[s * 511 + j], &sp, &cp);
    } else {  // identity pad pair (elements 1023/1024)
      ct = 1.f; st = 0.f; cp = 0.f; sp = 1.f;
    }
    // transposed slot: lane = j>>3 owns pair j as its (j&7)-th register
    ((f4*)ws)[s * 1024 + phase * 512 + (j & 7) * 64 + (j >> 3)] =
        (f4){ct, st, cp, sp};
  } else if (tid < 16896) {
    int m = tid - 16384;  // f4 index covering elements 2m, 2m+1
    float s0, c0, s1, c1;
    sincosf(omega[2 * m], &s0, &c0);
    sincosf(omega[2 * m + 1], &s1, &c1);
    ((f4*)(ws + OMCS_OFF))[(m & 7) * 64 + (m >> 3)] = (f4){c0, s0, c1, s1};
  }
}

// One wave owns R rows; lane l owns elements 16l..16l+15 (8 even pairs).
// Even rotations register-local; odd rotations register-local except one
// boundary pair per lane (intra-wave shfl). Coeffs come from a block-shared
// LDS double buffer; step s+1 is prefetched (global->reg at step top,
// reg->LDS at step end) while step s computes.
template <int R>
__global__ __launch_bounds__(256, 2) void eunn_main(
    const float* __restrict__ x, float* __restrict__ out,
    const float* __restrict__ ws) {
  __shared__ f4 cbuf[2][1024];  // 2 x 16KB: [step parity][transposed slot]
  const int tid = threadIdx.x;
  const int lane = tid & 63;
  const int wid = blockIdx.x * (blockDim.x >> 6) + (tid >> 6);
  const f4* wsf = (const f4*)ws;

  // ---- prologue: stage step 0 coeffs (issue before x loads; ds_write only
  // needs the staging subset -> compiler emits counted vmcnt) ----
  f4 p0 = wsf[tid], p1 = wsf[tid + 256], p2 = wsf[tid + 512], p3 = wsf[tid + 768];

  // e[r][p] = (re[16l+2p], im[16l+2p], re[16l+2p+1], im[16l+2p+1])
  f4 e[R][8];
#pragma unroll
  for (int r = 0; r < R; ++r) {
    const f4* xr = (const f4*)(x + (size_t)(wid * R + r) * 2048) + lane * 8;
#pragma unroll
    for (int p = 0; p < 8; ++p) e[r][p] = xr[p];
  }

  cbuf[0][tid] = p0;
  cbuf[0][tid + 256] = p1;
  cbuf[0][tid + 512] = p2;
  cbuf[0][tid + 768] = p3;
  __syncthreads();

#pragma unroll 1
  for (int s = 0; s < 16; ++s) {
    const int cur = s & 1, nxt = cur ^ 1;
    // ---- issue next step's staging loads (consumed at step end) ----
    const f4* nb = wsf + ((s + 1) & 15) * 1024;
    f4 n0 = nb[tid], n1 = nb[tid + 256], n2 = nb[tid + 512], n3 = nb[tid + 768];

    // ---- read this step's coeffs from LDS (E first; O completes during even) ----
    f4 E[8], O[8];
#pragma unroll
    for (int p = 0; p < 8; ++p) E[p] = cbuf[cur][p * 64 + lane];
#pragma unroll
    for (int p = 0; p < 8; ++p) O[p] = cbuf[cur][512 + p * 64 + lane];

    // ---- even rotation: pair j=8l+p couples (e.x,e.y) and (e.z,e.w) ----
#pragma unroll
    for (int r = 0; r < R; ++r) {
#pragma unroll
      for (int p = 0; p < 8; ++p) {
        f4 c = E[p];
        f4 v = e[r][p];
        float t0 = c.x * v.x - c.y * v.z;
        float t1 = c.x * v.y - c.y * v.w;
        e[r][p] = (f4){c.w * t0 - c.z * t1, c.z * t0 + c.w * t1,
                       c.y * v.x + c.x * v.z, c.y * v.y + c.x * v.w};
      }
    }

    // ---- odd rotation: pair j couples elements 2j+1, 2j+2 ----
    {
      // neighbor pair (8l-1)'s (ct,st) from lane l-1; identity at lane 0
      float ctm = __shfl_up(O[7].x, 1, 64);
      float stm = __shfl_up(O[7].y, 1, 64);
      if (lane == 0) { ctm = 1.f; stm = 0.f; }
#pragma unroll
      for (int r = 0; r < R; ++r) {
        float upx = __shfl_down(e[r][0].x, 1, 64);  // elem 16l+16 (pre)
        float upy = __shfl_down(e[r][0].y, 1, 64);
        float dnz = __shfl_up(e[r][7].z, 1, 64);    // elem 16l-1 (pre)
        float dnw = __shfl_up(e[r][7].w, 1, 64);
        // element 16l = second half of pair 8l-1
        float nx = stm * dnz + ctm * e[r][0].x;
        float ny = stm * dnw + ctm * e[r][0].y;
        e[r][0].x = nx;
        e[r][0].y = ny;
        // interior odd pairs j=8l+p, p=0..6
#pragma unroll
        for (int p = 0; p < 7; ++p) {
          f4 c = O[p];
          float e0r = e[r][p].z, e0i = e[r][p].w;
          float e1r = e[r][p + 1].x, e1i = e[r][p + 1].y;
          float t0 = c.x * e0r - c.y * e1r;
          float t1 = c.x * e0i - c.y * e1i;
          e[r][p].z = c.w * t0 - c.z * t1;
          e[r][p].w = c.z * t0 + c.w * t1;
          e[r][p + 1].x = c.y * e0r + c.x * e1r;
          e[r][p + 1].y = c.y * e0i + c.x * e1i;
        }
        // boundary pair j=8l+7 (second element lives in lane l+1; lane 63 = identity)
        {
          f4 c = O[7];
          float e0r = e[r][7].z, e0i = e[r][7].w;
          float t0 = c.x * e0r - c.y * upx;
          float t1 = c.x * e0i - c.y * upy;
          e[r][7].z = c.w * t0 - c.z * t1;
          e[r][7].w = c.z * t0 + c.w * t1;
        }
      }
    }

    // ---- commit next step's coeffs to the other buffer ----
    cbuf[nxt][tid] = n0;
    cbuf[nxt][tid + 256] = n1;
    cbuf[nxt][tid + 512] = n2;
    cbuf[nxt][tid + 768] = n3;
    __syncthreads();
  }

  // ---- final diagonal phase + store ----
  const f4* om4 = (const f4*)(ws + OMCS_OFF) + lane;  // (c,s,c,s), + p*64
#pragma unroll
  for (int r = 0; r < R; ++r) {
    f4* outr = (f4*)(out + (size_t)(wid * R + r) * 2048) + lane * 8;
#pragma unroll
    for (int p = 0; p < 8; ++p) {
      f4 v = e[r][p];
      f4 w = om4[p * 64];
      outr[p] = (f4){v.x * w.x - v.y * w.y, v.x * w.y + v.y * w.x,
                     v.z * w.z - v.w * w.w, v.z * w.w + v.w * w.z};
    }
  }
}

extern "C" void kernel_launch(void* const* d_in, const int* in_sizes, int n_in,
                              void* d_out, int out_size, void* d_ws, size_t ws_size,
                              hipStream_t stream) {
  const float* x     = (const float*)d_in[0];  // (4096,1024,2)
  const float* omega = (const float*)d_in[1];  // (1024,)
  const float* et    = (const float*)d_in[2];  // (16,512)
  const float* ot    = (const float*)d_in[3];  // (16,511)
  const float* ep    = (const float*)d_in[4];  // (16,512)
  const float* op    = (const float*)d_in[5];  // (16,511)
  float* out = (float*)d_out;
  float* ws  = (float*)d_ws;

  // 16896 jobs: 16x1024 coeff quads + 512 omega f4 entries
  eunn_precompute<<<dim3(66), dim3(256), 0, stream>>>(omega, et, ot, ep, op, ws);

  // R=2 rows/wave: 2048 waves, 4 waves/block -> 512 blocks (2 blocks/CU)
  eunn_main<2><<<dim3(512), dim3(256), 0, stream>>>(x, out, ws);
}